// Round 12
// baseline (5484.621 us; speedup 1.0000x reference)
//
#include <hip/hip_runtime.h>
#include <hip/hip_bf16.h>
#include <math.h>

#define DEVI __device__ __forceinline__
typedef unsigned long long ull;
typedef float f32x2 __attribute__((ext_vector_type(2)));

// ---------------------------------------------------------------- FPS
// r12: DUAL-BATCH INTERLEAVED chains per wave (ILP latency hiding):
// computeA -> publishA -> computeB -> publishB -> pollA -> pollB.
// Winner coords ride the publish payload (r5-VERIFIED 3-slot protocol:
// write order mXY, mZ(it-tag), mK(it-tag); in-order per-wave LDS commit =>
// both tags fresh implies payload committed). Poll = r6-VERIFIED plain
// loads + asm memory clobber (batched, 1 LDS round-trip/trip). Reduce =
// r8-VERIFIED split DPP max chain + min-index chain. Double-buffer safety =
// r4-verified argument. No LDS point copy, no dependent coords read.
DEVI f32x2 pk_sub(f32x2 a, f32x2 b){
  f32x2 r;
  asm("v_pk_add_f32 %0, %1, %2 neg_lo:[0,1] neg_hi:[0,1]" : "=v"(r) : "v"(a), "v"(b));
  return r;
}
DEVI f32x2 pk_mul(f32x2 a, f32x2 b){
  f32x2 r; asm("v_pk_mul_f32 %0, %1, %2" : "=v"(r) : "v"(a), "v"(b)); return r;
}
DEVI f32x2 pk_add(f32x2 a, f32x2 b){
  f32x2 r; asm("v_pk_add_f32 %0, %1, %2" : "=v"(r) : "v"(a), "v"(b)); return r;
}

template<int CTRL>
DEVI float dppmaxf(float x){
  float o = __int_as_float(__builtin_amdgcn_update_dpp(__float_as_int(x),__float_as_int(x),CTRL,0xF,0xF,false));
  return fmaxf(x,o);
}
template<int CTRL>
DEVI unsigned dppminu(unsigned x){
  unsigned o = (unsigned)__builtin_amdgcn_update_dpp((int)x,(int)x,CTRL,0xF,0xF,false);
  return (x < o) ? x : o;
}

// compute + publish one chain's iteration (r8 reduce + payload publish).
// slotbuf layout (12 x u64): [0..3]=mK, [4..7]=mXY, [8..11]=mZ(it-tag).
template<int P>
DEVI void fps_compute_publish(f32x2 (&px)[P/2], f32x2 (&py)[P/2], f32x2 (&pz)[P/2],
                              float (&dist)[P],
                              float sx, float sy, float sz,
                              unsigned itu, ull* slotbuf, int tid)
{
  const int wv = tid>>6, lane = tid&63;
  f32x2 vsx, vsy, vsz;
  vsx.x=sx; vsx.y=sx; vsy.x=sy; vsy.y=sy; vsz.x=sz; vsz.y=sz;
  float bv = -1.f;
  #pragma unroll
  for (int i=0;i<P/2;i++){
    f32x2 dx = pk_sub(px[i], vsx);
    f32x2 dy = pk_sub(py[i], vsy);
    f32x2 dz = pk_sub(pz[i], vsz);
    f32x2 s  = pk_add(pk_add(pk_mul(dx,dx), pk_mul(dy,dy)), pk_mul(dz,dz));
    float d0 = fminf(dist[2*i],   s.x);
    float d1 = fminf(dist[2*i+1], s.y);
    dist[2*i] = d0; dist[2*i+1] = d1;
    bv = fmaxf(bv, d0);
    bv = fmaxf(bv, d1);
  }
  int bidx = 0;
  #pragma unroll
  for (int p=P-1;p>=0;p--) if (dist[p]==bv) bidx = tid+(p<<8);
  float w = bv;
  w = dppmaxf<0x111>(w);
  w = dppmaxf<0x112>(w);
  w = dppmaxf<0x114>(w);
  w = dppmaxf<0x118>(w);
  w = dppmaxf<0x142>(w);
  w = dppmaxf<0x143>(w);   // lane63 = wave max
  float bvw = __uint_as_float((unsigned)__builtin_amdgcn_readlane(__float_as_int(w),63));
  unsigned cand = (bv == bvw) ? (unsigned)bidx : 0xFFFFFFFFu;
  cand = dppminu<0x111>(cand);
  cand = dppminu<0x112>(cand);
  cand = dppminu<0x114>(cand);
  cand = dppminu<0x118>(cand);
  cand = dppminu<0x142>(cand);
  cand = dppminu<0x143>(cand);               // lane63 = wave-min match idx
  unsigned candw = (unsigned)__builtin_amdgcn_readlane((int)cand,63); // uniform
  // winner-lane coords: uniform wp register-select, then readlane broadcast
  int wp = (int)(candw >> 8);
  float bx = px[0].x, by = py[0].x, bz = pz[0].x;
  #pragma unroll
  for (int i=0;i<P/2;i++){
    if (wp == 2*i  ){ bx=px[i].x; by=py[i].x; bz=pz[i].x; }
    if (wp == 2*i+1){ bx=px[i].y; by=py[i].y; bz=pz[i].y; }
  }
  int wlane = (int)(candw & 63u);
  bx = __uint_as_float((unsigned)__builtin_amdgcn_readlane(__float_as_int(bx), wlane));
  by = __uint_as_float((unsigned)__builtin_amdgcn_readlane(__float_as_int(by), wlane));
  bz = __uint_as_float((unsigned)__builtin_amdgcn_readlane(__float_as_int(bz), wlane));
  if (lane==63){
    volatile ull* sb = (volatile ull*)slotbuf;
    sb[4+wv] = ((ull)__float_as_uint(by)<<32) | (ull)__float_as_uint(bx);
    sb[8+wv] = ((ull)itu<<32) | (ull)__float_as_uint(bz);
    unsigned lo = ((~candw & 0xFFFu)<<12) | itu;        // r6-verified encoding
    sb[wv]   = ((ull)__float_as_uint(bvw)<<32) | (ull)lo;
  }
}

// poll + merge (r6 poll style, r5-verified merge shape); outputs winner.
DEVI void fps_poll_merge(const ull* slotbuf, unsigned itu,
                         float& sx, float& sy, float& sz, int& gi)
{
  ull k0,k1,k2,k3,a0,a1,a2,a3,z0,z1,z2,z3;
  for (;;){
    asm volatile("" ::: "memory");     // force re-read, allow batching
    k0=slotbuf[0]; k1=slotbuf[1]; k2=slotbuf[2]; k3=slotbuf[3];
    a0=slotbuf[4]; a1=slotbuf[5]; a2=slotbuf[6]; a3=slotbuf[7];
    z0=slotbuf[8]; z1=slotbuf[9]; z2=slotbuf[10]; z3=slotbuf[11];
    unsigned chk = (((unsigned)k0 ^ itu) | ((unsigned)k1 ^ itu) |
                    ((unsigned)k2 ^ itu) | ((unsigned)k3 ^ itu)) & 0xFFFu;
    chk |= ((unsigned)(z0>>32) ^ itu) | ((unsigned)(z1>>32) ^ itu) |
           ((unsigned)(z2>>32) ^ itu) | ((unsigned)(z3>>32) ^ itu);
    if (chk == 0u) break;
  }
  bool tA = (k1 > k0);
  ull ka = tA?k1:k0, aa = tA?a1:a0, za = tA?z1:z0;
  bool tB = (k3 > k2);
  ull kb = tB?k3:k2, ab = tB?a3:a2, zb = tB?z3:z2;
  bool tC = (kb > ka);
  ull kw = tC?kb:ka, aw = tC?ab:aa, zw = tC?zb:za;
  sx = __uint_as_float((unsigned)aw);
  sy = __uint_as_float((unsigned)(aw>>32));
  sz = __uint_as_float((unsigned)zw);
  gi = (int)((~((unsigned)(kw & 0xffffffffull) >> 12)) & 0xFFFu);
}

// dual-chain stage: two independent batches on the same 4 waves.
template<int P>
DEVI void fps_stage_dual(f32x2 (&pxA)[P/2], f32x2 (&pyA)[P/2], f32x2 (&pzA)[P/2],
                         f32x2 (&pxB)[P/2], f32x2 (&pyB)[P/2], f32x2 (&pzB)[P/2],
                         int m,
                         float sxA, float syA, float szA,
                         float sxB, float syB, float szB,
                         ull (&slA)[2][12], ull (&slB)[2][12],
                         int* sselA, int* sselB,
                         float* snxA, float* snyA, float* snzA,
                         float* snxB, float* snyB, float* snzB, int tid)
{
  float distA[P], distB[P];
  #pragma unroll
  for (int p=0;p<P;p++){ distA[p]=1e10f; distB[p]=1e10f; }
  if (tid==0){
    sselA[0]=0; snxA[0]=sxA; snyA[0]=syA; snzA[0]=szA;
    sselB[0]=0; snxB[0]=sxB; snyB[0]=syB; snzB[0]=szB;
  }
  #pragma unroll 1
  for (int it=1; it<m; it++){
    const unsigned itu = (unsigned)it;
    fps_compute_publish<P>(pxA,pyA,pzA,distA, sxA,syA,szA, itu, slA[it&1], tid);
    fps_compute_publish<P>(pxB,pyB,pzB,distB, sxB,syB,szB, itu, slB[it&1], tid);
    int giA, giB;
    fps_poll_merge(slA[it&1], itu, sxA,syA,szA, giA);
    fps_poll_merge(slB[it&1], itu, sxB,syB,szB, giB);
    if (tid==0){
      sselA[it]=giA; snxA[it]=sxA; snyA[it]=syA; snzA[it]=szA;
      sselB[it]=giB; snxB[it]=sxB; snyB[it]=syB; snzB[it]=szB;
    }
  }
}

// ----------------------------------------- KNN wave body (one wave = one q)
// (r3/r4/r6-verified) Scratch-free top-16 with EXACT bitmask exclusion.
template<int CTRL>
DEVI void dppmin_fj(float& d, int& j){
  float od = __int_as_float(__builtin_amdgcn_update_dpp(__float_as_int(d),__float_as_int(d),CTRL,0xF,0xF,false));
  int   oj = __builtin_amdgcn_update_dpp(j,j,CTRL,0xF,0xF,false);
  bool tk = (od < d) || (od == d && oj < j);
  d = tk?od:d; j = tk?oj:j;
}

DEVI float dist_qk(const float* __restrict__ ckb, int j,
                   float qx, float qy, float qz, float sqq){
  float kx=ckb[3*j], ky=ckb[3*j+1], kz=ckb[3*j+2];
  float sk  = __fadd_rn(__fadd_rn(__fmul_rn(kx,kx),__fmul_rn(ky,ky)),
                        __fmul_rn(kz,kz));
  float dot = __fadd_rn(__fadd_rn(__fmul_rn(qx,kx),__fmul_rn(qy,ky)),
                        __fmul_rn(qz,kz));
  return __fadd_rn(__fsub_rn(sqq, __fmul_rn(2.0f,dot)), sk);
}

template<int NPL>   // points per lane = Nk/64; NPL in {64,32,8,2}
DEVI void knn_wave(const float* __restrict__ cq, int Nq,
                   const float* __restrict__ ck, int Nk,
                   int* __restrict__ idx_out, int b, int q, int lane)
{
  size_t r3 = ((size_t)b*Nq+q)*3;
  float qx=cq[r3], qy=cq[r3+1], qz=cq[r3+2];
  float sqq = __fadd_rn(__fadd_rn(__fmul_rn(qx,qx),__fmul_rn(qy,qy)),
                        __fmul_rn(qz,qz));
  constexpr int GS = (NPL < 8) ? NPL : 8;
  constexpr int NG = NPL / GS;
  float gv[NG]; int gj[NG];
  const float* ckb = ck + (size_t)b*Nk*3;
  ull exmask = 0;                 // bit i: this lane's element i extracted
  int dirtyg = -1;                // -1 => rebuild all groups (round 0)
  int myout = 0;
  #pragma unroll 1
  for (int r=0; r<16; r++){
    #pragma unroll
    for (int g=0; g<NG; g++){
      if (dirtyg < 0 || dirtyg == g){          // wave-uniform branch
        float nv=__int_as_float(0x7f800000); int nj=0x7fffffff;
        #pragma unroll
        for (int e=0; e<GS; e++){
          const int i = g*GS+e;                // compile-time bit index
          int j = lane + (i<<6);
          float d = dist_qk(ckb, j, qx,qy,qz, sqq);
          bool rem = ((exmask >> i) & 1ull) == 0ull;
          if (rem && d < nv){ nv=d; nj=j; }    // ascending j: strict < keeps first
        }
        gv[g]=nv; gj[g]=nj;
      }
    }
    float lv = gv[0]; int lj = gj[0];
    #pragma unroll
    for (int g=1; g<NG; g++)
      if (gv[g]<lv || (gv[g]==lv && gj[g]<lj)){ lv=gv[g]; lj=gj[g]; }
    float rd = lv; int rj = lj;
    dppmin_fj<0x111>(rd,rj);
    dppmin_fj<0x112>(rd,rj);
    dppmin_fj<0x114>(rd,rj);
    dppmin_fj<0x118>(rd,rj);
    dppmin_fj<0x142>(rd,rj);
    dppmin_fj<0x143>(rd,rj);                   // lane63 = global lex-min
    int wj = __builtin_amdgcn_readlane(rj,63); // wave-uniform winner
    if (lane == r) myout = wj;
    if ((wj & 63) == lane) exmask |= (1ull << (wj>>6));   // exact exclusion
    dirtyg = (wj>>6)/GS;
  }
  if (lane<16) idx_out[((size_t)b*Nq+q)*16 + lane] = myout;
}

// ------ fused: dual-batch FPS (blocks 0..3) + layer-1 KNN (blocks 4..)
// ~80 KB LDS -> KNN co-residency 2 blocks/CU.
__global__ __launch_bounds__(256) void k_fps_knn1(
    const float* __restrict__ coords0,
    int* __restrict__ idx1, int* __restrict__ idx2, int* __restrict__ idx3,
    float* __restrict__ c1, float* __restrict__ c2, float* __restrict__ c3,
    float* __restrict__ out, int* __restrict__ knn1)
{
  __shared__ float s2x[2][2048], s2y[2][2048], s2z[2][2048];  // 48 KB staging
  __shared__ float s3x[2][512],  s3y[2][512],  s3z[2][512];   // 12 KB
  __shared__ float s4x[2][128],  s4y[2][128],  s4z[2][128];   //  3 KB
  __shared__ int   ssel[2][2048];                             // 16 KB
  __shared__ alignas(32) ull slots[2][2][12];                 // [batch][buf][12]
  if (blockIdx.x >= 4){
    int flat = blockIdx.x - 4;                       // 1024 blocks per batch
    int b = flat >> 10, qb = flat & 1023;
    int q = qb*4 + (threadIdx.x>>6);                 // 4 waves -> 4 queries
    knn_wave<64>(coords0, 4096, coords0, 4096, knn1, b, q, threadIdx.x&63);
    return;
  }
  const int tid = threadIdx.x;
  const int bA = blockIdx.x*2, bB = bA+1;
  __builtin_amdgcn_s_setprio(3);                     // protect FPS issue slots
  const float* cbA = coords0 + (size_t)bA*4096*3;
  const float* cbB = coords0 + (size_t)bB*4096*3;
  if (tid<48) ((ull*)slots)[tid] = ~0ull;            // tags never-valid
  { // stage 1: 4096 -> 2048  (P=16 per chain, j = tid + p*256, global->regs)
    f32x2 pxA[8], pyA[8], pzA[8], pxB[8], pyB[8], pzB[8];
    #pragma unroll
    for (int i=0;i<8;i++){
      int j0 = tid + ((2*i)<<8), j1 = tid + ((2*i+1)<<8);
      pxA[i].x=cbA[3*j0]; pyA[i].x=cbA[3*j0+1]; pzA[i].x=cbA[3*j0+2];
      pxA[i].y=cbA[3*j1]; pyA[i].y=cbA[3*j1+1]; pzA[i].y=cbA[3*j1+2];
      pxB[i].x=cbB[3*j0]; pyB[i].x=cbB[3*j0+1]; pzB[i].x=cbB[3*j0+2];
      pxB[i].y=cbB[3*j1]; pyB[i].y=cbB[3*j1+1]; pzB[i].y=cbB[3*j1+2];
    }
    float sxA=cbA[0], syA=cbA[1], szA=cbA[2];
    float sxB=cbB[0], syB=cbB[1], szB=cbB[2];
    __syncthreads();
    fps_stage_dual<16>(pxA,pyA,pzA, pxB,pyB,pzB, 2048,
                       sxA,syA,szA, sxB,syB,szB,
                       slots[0], slots[1], ssel[0], ssel[1],
                       s2x[0],s2y[0],s2z[0], s2x[1],s2y[1],s2z[1], tid);
  }
  __syncthreads();                 // all waves out of stage-1 polls
  { // flush stage 1 (both batches)
    #pragma unroll
    for (int g=0; g<2; g++){
      int b = bA + g;
      float* c1b = c1 + (size_t)b*2048*3;
      for (int i=tid;i<2048;i+=256){
        idx1[b*2048+i]=ssel[g][i];
        c1b[3*i]=s2x[g][i]; c1b[3*i+1]=s2y[g][i]; c1b[3*i+2]=s2z[g][i];
      }
    }
  }
  __syncthreads();                 // flush reads done before ssel rewrite
  { // stage 2: 2048 -> 512   (P=8 per chain, coords from staging LDS)
    f32x2 pxA[4], pyA[4], pzA[4], pxB[4], pyB[4], pzB[4];
    #pragma unroll
    for (int i=0;i<4;i++){
      int j0 = tid + ((2*i)<<8), j1 = tid + ((2*i+1)<<8);
      pxA[i].x=s2x[0][j0]; pyA[i].x=s2y[0][j0]; pzA[i].x=s2z[0][j0];
      pxA[i].y=s2x[0][j1]; pyA[i].y=s2y[0][j1]; pzA[i].y=s2z[0][j1];
      pxB[i].x=s2x[1][j0]; pyB[i].x=s2y[1][j0]; pzB[i].x=s2z[1][j0];
      pxB[i].y=s2x[1][j1]; pyB[i].y=s2y[1][j1]; pzB[i].y=s2z[1][j1];
    }
    float sxA=s2x[0][0], syA=s2y[0][0], szA=s2z[0][0];
    float sxB=s2x[1][0], syB=s2y[1][0], szB=s2z[1][0];
    __syncthreads();
    fps_stage_dual<8>(pxA,pyA,pzA, pxB,pyB,pzB, 512,
                      sxA,syA,szA, sxB,syB,szB,
                      slots[0], slots[1], ssel[0], ssel[1],
                      s3x[0],s3y[0],s3z[0], s3x[1],s3y[1],s3z[1], tid);
  }
  __syncthreads();                 // all waves out of stage-2 polls
  {
    #pragma unroll
    for (int g=0; g<2; g++){
      int b = bA + g;
      float* c2b = c2 + (size_t)b*512*3;
      for (int i=tid;i<512;i+=256){
        idx2[b*512+i]=ssel[g][i];
        c2b[3*i]=s3x[g][i]; c2b[3*i+1]=s3y[g][i]; c2b[3*i+2]=s3z[g][i];
      }
    }
  }
  __syncthreads();
  { // stage 3: 512 -> 128    (P=2 per chain)
    f32x2 pxA[1], pyA[1], pzA[1], pxB[1], pyB[1], pzB[1];
    {
      int j0 = tid, j1 = tid + 256;
      pxA[0].x=s3x[0][j0]; pyA[0].x=s3y[0][j0]; pzA[0].x=s3z[0][j0];
      pxA[0].y=s3x[0][j1]; pyA[0].y=s3y[0][j1]; pzA[0].y=s3z[0][j1];
      pxB[0].x=s3x[1][j0]; pyB[0].x=s3y[1][j0]; pzB[0].x=s3z[1][j0];
      pxB[0].y=s3x[1][j1]; pyB[0].y=s3y[1][j1]; pzB[0].y=s3z[1][j1];
    }
    float sxA=s3x[0][0], syA=s3y[0][0], szA=s3z[0][0];
    float sxB=s3x[1][0], syB=s3y[1][0], szB=s3z[1][0];
    __syncthreads();
    fps_stage_dual<2>(pxA,pyA,pzA, pxB,pyB,pzB, 128,
                      sxA,syA,szA, sxB,syB,szB,
                      slots[0], slots[1], ssel[0], ssel[1],
                      s4x[0],s4y[0],s4z[0], s4x[1],s4y[1],s4z[1], tid);
  }
  __syncthreads();
  {
    #pragma unroll
    for (int g=0; g<2; g++){
      int b = bA + g;
      float* c3b = c3 + (size_t)b*128*3;
      float* ob  = out + (size_t)b*128*3;
      for (int i=tid;i<128;i+=256){
        idx3[b*128+i]=ssel[g][i];
        float X=s4x[g][i],Y=s4y[g][i],Z=s4z[g][i];
        c3b[3*i]=X; c3b[3*i+1]=Y; c3b[3*i+2]=Z;
        ob[3*i]=X; ob[3*i+1]=Y; ob[3*i+2]=Z;
      }
    }
  }
}

// --------------- weight split+transpose (all 6 layers) + fused stats zero
struct WtParams {
  const float* W[6];
  float* wl[6];
  float* wq[6];
  int O[6], C[6], OC[6];
};
__global__ void k_wt_all(WtParams p, float* __restrict__ stats){
  int s = blockIdx.y;
  int t = blockIdx.x*blockDim.x + threadIdx.x;
  if (s==0 && t<384) stats[t] = 0.f;           // fused k_zero
  int OC = p.OC[s];
  if (t >= OC) return;
  int C = p.C[s], O = p.O[s];
  int o = t / C, c = t - o*C;
  const float* W = p.W[s];
  float wlv = W[o*2*C + c];
  float wrv = W[o*2*C + C + c];
  p.wl[s][c*O+o] = wlv;
  p.wq[s][c*O+o] = wrv - wlv;
}

// ---------------- fused per-layer: KNN (blocks 0..gknn-1) + dual GEMM (rest)
// (r11-verified) staging folds the producer transform (conv / GN+leaky).
#define GEMM_M 8
template<int NPL, int MODE>
__global__ __launch_bounds__(256,3) void k_knn_gemm(
    const float* __restrict__ cq, int Nq,
    const float* __restrict__ ck, int Nk, int* __restrict__ knnidx,
    const float* __restrict__ fsrc,            // MODE0: x ; MODE1: vm
    const float* __restrict__ w_in, const float* __restrict__ b_in,
    const float* __restrict__ stats, const float* __restrict__ gamma,
    const float* __restrict__ beta, float invcnt,
    int C, int O,
    const float* __restrict__ wlT, const float* __restrict__ wqT,
    float* __restrict__ yk, float* __restrict__ yq, int gknn)
{
  const int b = blockIdx.y;
  if ((int)blockIdx.x < gknn){
    int q = blockIdx.x*4 + (threadIdx.x>>6);
    if (q < Nq) knn_wave<NPL>(cq, Nq, ck, Nk, knnidx, b, q, threadIdx.x&63);
    return;
  }
  const int bx = blockIdx.x - gknn;
  extern __shared__ float sf[];                  // rowsPB x (C+1) padded tile
  const int o = threadIdx.x & (O-1);
  const int rg = threadIdx.x / O;
  const int R = blockDim.x / O;
  const int rowsPB = R*GEMM_M;
  const int row0 = bx * rowsPB;
  const int Cp = C+1;
  if (MODE == 0){
    const float* xb = fsrc + (size_t)b*Nk*3;
    for (int i=threadIdx.x; i<rowsPB*C; i+=blockDim.x){
      int r = i / C, c = i - r*C;
      int row = row0 + r;
      float cx=xb[row*3], cy=xb[row*3+1], cz=xb[row*3+2];
      float s = __fadd_rn(__fadd_rn(__fmul_rn(cx,w_in[c*3+0]),
                                    __fmul_rn(cy,w_in[c*3+1])),
                          __fmul_rn(cz,w_in[c*3+2]));
      sf[r*Cp + c] = __fadd_rn(s, b_in[c]);
    }
  } else {
    const float* src = fsrc + ((size_t)b*Nk + row0)*C;
    for (int i=threadIdx.x; i<rowsPB*C; i+=blockDim.x){
      int r = i / C, c = i - r*C;
      int g = (c*4)/C;
      float s1 = stats[b*8+g*2], s2 = stats[b*8+g*2+1];
      float mu = s1*invcnt;
      float var = fmaf(-mu,mu, s2*invcnt);
      float rs = 1.0f/sqrtf(var+1e-5f);
      float v = (src[i]-mu)*rs*gamma[c] + beta[c];
      sf[r*Cp + c] = (v>=0.f)? v : 0.2f*v;
    }
  }
  __syncthreads();
  float ak[GEMM_M], aq[GEMM_M];
  #pragma unroll
  for (int m=0;m<GEMM_M;m++){ ak[m]=0.f; aq[m]=0.f; }
  const float* lp = wlT + o;
  const float* qp = wqT + o;
  const float* sfr = sf + rg*GEMM_M*Cp;
  for (int c=0;c<C;c++){
    float wl = lp[(size_t)c*O];
    float wq = qp[(size_t)c*O];
    #pragma unroll
    for (int m=0;m<GEMM_M;m++){
      float xv = sfr[m*Cp + c];
      ak[m] = fmaf(xv, wl, ak[m]);
      aq[m] = fmaf(xv, wq, aq[m]);
    }
  }
  size_t obase = ((size_t)b*Nk + row0 + rg*GEMM_M)*O + o;
  #pragma unroll
  for (int m=0;m<GEMM_M;m++){
    yk[obase + (size_t)m*O] = ak[m];
    yq[obase + (size_t)m*O] = aq[m];
  }
}

// ---------------------------------- gather neighbors + max_k + GN statistics
__global__ void k_gather(const float* __restrict__ yk, const float* __restrict__ yq,
                         const int* __restrict__ knnidx, const int* __restrict__ qmap,
                         int Nq, int Nk, int O,
                         float* __restrict__ vmax, float* __restrict__ stats)
{
  const int b = blockIdx.y;
  const int o = threadIdx.x & (O-1);
  const int rg = threadIdx.x / O;
  const int R = blockDim.x / O;
  float ls=0.f, ls2=0.f;
  const float* ykb = yk + (size_t)b*Nk*O;
  const float* yqb = yq + (size_t)b*Nk*O;
  for (int nq = blockIdx.x*R + rg; nq < Nq; nq += gridDim.x*R){
    int qj = qmap ? qmap[b*Nq+nq] : nq;
    float vq = yqb[(size_t)qj*O + o];
    const int* ip = knnidx + ((size_t)b*Nq+nq)*16;
    float vmx = -3.4e38f;
    #pragma unroll
    for (int k=0;k<16;k++){
      int j = ip[k];
      float v = ykb[(size_t)j*O+o] + vq;
      vmx = fmaxf(vmx, v);
      ls += v; ls2 = fmaf(v,v,ls2);
    }
    vmax[((size_t)b*Nq+nq)*O+o] = vmx;
  }
  int span = O/4; if (span>64) span=64;          // group-aligned lane segments
  for (int mm=1; mm<span; mm<<=1){
    ls  += __shfl_xor(ls, mm);
    ls2 += __shfl_xor(ls2, mm);
  }
  __shared__ float sred[8];
  if (threadIdx.x<8) sred[threadIdx.x]=0.f;
  __syncthreads();
  int lane = threadIdx.x & 63;
  if ((lane & (span-1))==0){
    int g = (o*4)/O;
    atomicAdd(&sred[g*2+0], ls);
    atomicAdd(&sred[g*2+1], ls2);
  }
  __syncthreads();
  if (threadIdx.x<8) atomicAdd(&stats[b*8+threadIdx.x], sred[threadIdx.x]);
}

// ---------------------------------------------- GN normalize + leaky (on max)
// Only needed for the FINAL layer (7) whose output goes to d_out.
__global__ void k_norm(const float* __restrict__ vmax, const float* __restrict__ stats,
                       const float* __restrict__ gamma,
                       const float* __restrict__ beta,
                       int Nq, int O, float invcnt, float* __restrict__ outf)
{
  const int b = blockIdx.y;
  const int n = Nq*O;
  for (int i = blockIdx.x*blockDim.x+threadIdx.x; i<n; i+=gridDim.x*blockDim.x){
    int o = i & (O-1);
    int g = (o*4)/O;
    float s1 = stats[b*8+g*2], s2 = stats[b*8+g*2+1];
    float mu = s1*invcnt;
    float var = fmaf(-mu,mu, s2*invcnt);
    float rs = 1.0f/sqrtf(var+1e-5f);
    float v = (vmax[(size_t)b*n + i]-mu)*rs*gamma[o] + beta[o];
    outf[(size_t)b*n + i] = (v>=0.f)? v : 0.2f*v;
  }
}

// ===========================================================================
extern "C" void kernel_launch(void* const* d_in, const int* in_sizes, int n_in,
                              void* d_out, int out_size, void* d_ws, size_t ws_size,
                              hipStream_t stream)
{
  const int B = 8;
  const float* x    = (const float*)d_in[0];
  const float* w_in = (const float*)d_in[4];
  const float* b_in = (const float*)d_in[5];
  const float *Wm[6], *Gm[6], *Bm[6];
  for (int i=0;i<6;i++){
    Wm[i]=(const float*)d_in[6+3*i];
    Gm[i]=(const float*)d_in[6+3*i+1];
    Bm[i]=(const float*)d_in[6+3*i+2];
  }
  float* ws = (float*)d_ws;
  float* out = (float*)d_out;
  const size_t OFF_C1=4030464,  OFF_C2=4079616, OFF_C3=4091904,
               OFF_YK=4094976,  OFF_YQ=6192128, OFF_VM=8289280,
               OFF_WL=9337856,  OFF_WQ=9468928, OFF_ST=9600000,
               OFF_I1=9600384,  OFF_I2=9616768, OFF_I3=9620864, OFF_KNN=9621888,
               TOTAL=10146176;  // ~40.6 MB
  if (ws_size < TOTAL*sizeof(float)) return;
  float *c1=ws+OFF_C1, *c2=ws+OFF_C2, *c3=ws+OFF_C3,
        *yk=ws+OFF_YK, *yq=ws+OFF_YQ, *vm=ws+OFF_VM, *stats=ws+OFF_ST;
  int *i1=(int*)(ws+OFF_I1), *i2=(int*)(ws+OFF_I2), *i3=(int*)(ws+OFF_I3),
      *knn=(int*)(ws+OFF_KNN);

  const int OCs[6]  = {256, 2048, 8192, 16384, 32768, 65536};
  const int OCoff[6]= {0,   256,  2304, 10496, 26880, 59648};

  struct St { int C,O,Nk,Nq; const float* cq; const float* ck;
              const int* qmap; };
  const St st[6] = {
    {8,   32, 4096, 4096, x,  x,  nullptr},   // layer 1 (conv fold)
    {32,  64, 4096, 2048, c1, x,  i1},        // layer 2
    {64, 128, 2048,  512, c2, c1, i2},        // layer 4
    {128,128,  512,  512, c2, c2, nullptr},   // layer 5
    {128,256,  512,  128, c3, c2, i3},        // layer 6
    {256,256,  128,  128, c3, c3, nullptr},   // layer 7
  };
  float invc[6];
  for (int s=0;s<6;s++)
    invc[s] = 1.0f / ((float)(st[s].O/4) * (float)st[s].Nq * 16.0f);

  WtParams wp;
  for (int s=0;s<6;s++){
    wp.W[s]=Wm[s];
    wp.wl[s]=ws+OFF_WL+OCoff[s];
    wp.wq[s]=ws+OFF_WQ+OCoff[s];
    wp.O[s]=st[s].O; wp.C[s]=st[s].C; wp.OC[s]=OCs[s];
  }
  k_wt_all<<<dim3(256,6), 256, 0, stream>>>(wp, stats);

  // dual-batch FPS (blocks 0..3) + layer-1 KNN (blocks 4..8195)
  k_fps_knn1<<<4 + 8*1024, 256, 0, stream>>>(x, i1, i2, i3, c1, c2, c3,
                                             out, knn);

  for (int s=0;s<6;s++){
    const St& S = st[s];
    int rowsPB = 2048 / S.O;                       // (256/O)*GEMM_M
    int ggemm = S.Nk / rowsPB;
    int gknn  = (s > 0) ? (S.Nq + 3)/4 : 0;
    dim3 gg(gknn + ggemm, B);
    size_t shb = (size_t)rowsPB * (S.C+1) * sizeof(float);
    const float* wl = ws+OFF_WL+OCoff[s];
    const float* wqp = ws+OFF_WQ+OCoff[s];
    const float* stp = (s>0) ? (stats + (s-1)*64) : nullptr;
    const float* gp  = (s>0) ? Gm[s-1] : nullptr;
    const float* bp  = (s>0) ? Bm[s-1] : nullptr;
    float ivc = (s>0) ? invc[s-1] : 0.f;
    int npl = S.Nk >> 6;           // 64, 32, 8, 2
    if      (s == 0)
      k_knn_gemm< 2,0><<<gg, 256, shb, stream>>>(S.cq,S.Nq,S.ck,S.Nk,knn,
        x, w_in, b_in, nullptr, nullptr, nullptr, 0.f,
        S.C, S.O, wl, wqp, yk, yq, gknn);
    else if (npl == 64)
      k_knn_gemm<64,1><<<gg, 256, shb, stream>>>(S.cq,S.Nq,S.ck,S.Nk,knn,
        vm, nullptr, nullptr, stp, gp, bp, ivc,
        S.C, S.O, wl, wqp, yk, yq, gknn);
    else if (npl == 32)
      k_knn_gemm<32,1><<<gg, 256, shb, stream>>>(S.cq,S.Nq,S.ck,S.Nk,knn,
        vm, nullptr, nullptr, stp, gp, bp, ivc,
        S.C, S.O, wl, wqp, yk, yq, gknn);
    else if (npl ==  8)
      k_knn_gemm< 8,1><<<gg, 256, shb, stream>>>(S.cq,S.Nq,S.ck,S.Nk,knn,
        vm, nullptr, nullptr, stp, gp, bp, ivc,
        S.C, S.O, wl, wqp, yk, yq, gknn);
    else
      k_knn_gemm< 2,1><<<gg, 256, shb, stream>>>(S.cq,S.Nq,S.ck,S.Nk,knn,
        vm, nullptr, nullptr, stp, gp, bp, ivc,
        S.C, S.O, wl, wqp, yk, yq, gknn);
    dim3 gs(64, B);
    k_gather<<<gs, 256, 0, stream>>>(yk, yq, knn, S.qmap, S.Nq, S.Nk, S.O,
                                     vm, stats + s*64);
  }
  // final layer's GN+leaky -> d_out features
  {
    dim3 gn((128*256 + 255)/256, B);
    k_norm<<<gn, 256, 0, stream>>>(vm, stats + 5*64, Gm[5], Bm[5],
                                   128, 256, invc[5], out + 8*128*3);
  }
}

// Round 13
// 2292.254 us; speedup vs baseline: 2.3927x; 2.3927x over previous
//
#include <hip/hip_runtime.h>
#include <hip/hip_bf16.h>
#include <math.h>

#define DEVI __device__ __forceinline__
typedef unsigned long long ull;
typedef float f32x2 __attribute__((ext_vector_type(2)));

// ---------------------------------------------------------------- FPS
// r8/r11-VERIFIED 4-wave path (FROZEN — r4..r12 established the exchange
// floor): packed passA, fused DPP max chain + min-index chain, self-tagged
// u64 key, batched plain-load poll, coords from LDS point copy.
DEVI f32x2 pk_sub(f32x2 a, f32x2 b){
  f32x2 r;
  asm("v_pk_add_f32 %0, %1, %2 neg_lo:[0,1] neg_hi:[0,1]" : "=v"(r) : "v"(a), "v"(b));
  return r;
}
DEVI f32x2 pk_mul(f32x2 a, f32x2 b){
  f32x2 r; asm("v_pk_mul_f32 %0, %1, %2" : "=v"(r) : "v"(a), "v"(b)); return r;
}
DEVI f32x2 pk_add(f32x2 a, f32x2 b){
  f32x2 r; asm("v_pk_add_f32 %0, %1, %2" : "=v"(r) : "v"(a), "v"(b)); return r;
}

template<int CTRL>
DEVI float dppmaxf(float x){
  float o = __int_as_float(__builtin_amdgcn_update_dpp(__float_as_int(x),__float_as_int(x),CTRL,0xF,0xF,false));
  return fmaxf(x,o);
}
template<int CTRL>
DEVI unsigned dppminu(unsigned x){
  unsigned o = (unsigned)__builtin_amdgcn_update_dpp((int)x,(int)x,CTRL,0xF,0xF,false);
  return (x < o) ? x : o;
}

// ------- 4-wave stage (r8-verified)
template<int P>
DEVI void fps_stage(f32x2 (&px)[P/2], f32x2 (&py)[P/2], f32x2 (&pz)[P/2],
                    int m, float sx, float sy, float sz,
                    const float* cpx, const float* cpy, const float* cpz,
                    ull* mK,                      // [2][4] flattened, plain LDS
                    int* ssel, float* snx, float* sny, float* snz, int tid)
{
  const int wv = tid>>6, lane = tid&63;
  float dist[P];
  #pragma unroll
  for (int p=0;p<P;p++) dist[p]=1e10f;
  if (tid==0){ ssel[0]=0; if (snx){ snx[0]=sx; sny[0]=sy; snz[0]=sz; } }
  #pragma unroll 1
  for (int it=1; it<m; it++){
    f32x2 vsx, vsy, vsz;
    vsx.x=sx; vsx.y=sx; vsy.x=sy; vsy.y=sy; vsz.x=sz; vsz.y=sz;
    float bv = -1.f;
    #pragma unroll
    for (int i=0;i<P/2;i++){
      f32x2 dx = pk_sub(px[i], vsx);
      f32x2 dy = pk_sub(py[i], vsy);
      f32x2 dz = pk_sub(pz[i], vsz);
      f32x2 s  = pk_add(pk_add(pk_mul(dx,dx), pk_mul(dy,dy)), pk_mul(dz,dz));
      float d0 = fminf(dist[2*i],   s.x);
      float d1 = fminf(dist[2*i+1], s.y);
      dist[2*i] = d0; dist[2*i+1] = d1;
      bv = fmaxf(bv, d0);
      bv = fmaxf(bv, d1);
    }
    int bidx = 0;
    #pragma unroll
    for (int p=P-1;p>=0;p--) if (dist[p]==bv) bidx = tid+(p<<8);
    float w = bv;
    w = dppmaxf<0x111>(w);
    w = dppmaxf<0x112>(w);
    w = dppmaxf<0x114>(w);
    w = dppmaxf<0x118>(w);
    w = dppmaxf<0x142>(w);
    w = dppmaxf<0x143>(w);   // lane63 = wave max
    float bvw = __uint_as_float((unsigned)__builtin_amdgcn_readlane(__float_as_int(w),63));
    unsigned cand = (bv == bvw) ? (unsigned)bidx : 0xFFFFFFFFu;
    cand = dppminu<0x111>(cand);
    cand = dppminu<0x112>(cand);
    cand = dppminu<0x114>(cand);
    cand = dppminu<0x118>(cand);
    cand = dppminu<0x142>(cand);
    cand = dppminu<0x143>(cand);               // lane63 = wave-min match idx
    const unsigned itu = (unsigned)it;
    ull* slot = mK + ((it&1)<<2);
    if (lane==63){
      unsigned lo = ((~cand & 0xFFFu)<<12) | itu;       // r6-verified encoding
      *(volatile ull*)(slot + wv) = ((ull)__float_as_uint(bvw)<<32) | (ull)lo;
    }
    ull k0,k1,k2,k3;
    for (;;){
      asm volatile("" ::: "memory");     // force re-read, allow batching
      k0=slot[0]; k1=slot[1]; k2=slot[2]; k3=slot[3];
      unsigned chk = (((unsigned)k0 ^ itu) | ((unsigned)k1 ^ itu) |
                      ((unsigned)k2 ^ itu) | ((unsigned)k3 ^ itu)) & 0xFFFu;
      if (chk == 0u) break;
    }
    ull ka = (k1>k0)?k1:k0;
    ull kb = (k3>k2)?k3:k2;
    ull kw = (kb>ka)?kb:ka;
    int gi = (int)((~((unsigned)(kw & 0xffffffffull) >> 12)) & 0xFFFu);
    sx = cpx[gi]; sy = cpy[gi]; sz = cpz[gi];   // LDS broadcast reads
    if (tid==0){
      ssel[it]=gi;
      if (snx){ snx[it]=sx; sny[it]=sy; snz[it]=sz; }
    }
  }
}

// ----------------------------------------- KNN wave body (one wave = one q)
// (r3/r4/r6-verified) Scratch-free top-16 with EXACT bitmask exclusion.
template<int CTRL>
DEVI void dppmin_fj(float& d, int& j){
  float od = __int_as_float(__builtin_amdgcn_update_dpp(__float_as_int(d),__float_as_int(d),CTRL,0xF,0xF,false));
  int   oj = __builtin_amdgcn_update_dpp(j,j,CTRL,0xF,0xF,false);
  bool tk = (od < d) || (od == d && oj < j);
  d = tk?od:d; j = tk?oj:j;
}

DEVI float dist_qk(const float* __restrict__ ckb, int j,
                   float qx, float qy, float qz, float sqq){
  float kx=ckb[3*j], ky=ckb[3*j+1], kz=ckb[3*j+2];
  float sk  = __fadd_rn(__fadd_rn(__fmul_rn(kx,kx),__fmul_rn(ky,ky)),
                        __fmul_rn(kz,kz));
  float dot = __fadd_rn(__fadd_rn(__fmul_rn(qx,kx),__fmul_rn(qy,ky)),
                        __fmul_rn(qz,kz));
  return __fadd_rn(__fsub_rn(sqq, __fmul_rn(2.0f,dot)), sk);
}

template<int NPL>   // points per lane = Nk/64; NPL in {64,32,8,2}
DEVI void knn_wave(const float* __restrict__ cq, int Nq,
                   const float* __restrict__ ck, int Nk,
                   int* __restrict__ idx_out, int b, int q, int lane)
{
  size_t r3 = ((size_t)b*Nq+q)*3;
  float qx=cq[r3], qy=cq[r3+1], qz=cq[r3+2];
  float sqq = __fadd_rn(__fadd_rn(__fmul_rn(qx,qx),__fmul_rn(qy,qy)),
                        __fmul_rn(qz,qz));
  constexpr int GS = (NPL < 8) ? NPL : 8;
  constexpr int NG = NPL / GS;
  float gv[NG]; int gj[NG];
  const float* ckb = ck + (size_t)b*Nk*3;
  ull exmask = 0;                 // bit i: this lane's element i extracted
  int dirtyg = -1;                // -1 => rebuild all groups (round 0)
  int myout = 0;
  #pragma unroll 1
  for (int r=0; r<16; r++){
    #pragma unroll
    for (int g=0; g<NG; g++){
      if (dirtyg < 0 || dirtyg == g){          // wave-uniform branch
        float nv=__int_as_float(0x7f800000); int nj=0x7fffffff;
        #pragma unroll
        for (int e=0; e<GS; e++){
          const int i = g*GS+e;                // compile-time bit index
          int j = lane + (i<<6);
          float d = dist_qk(ckb, j, qx,qy,qz, sqq);
          bool rem = ((exmask >> i) & 1ull) == 0ull;
          if (rem && d < nv){ nv=d; nj=j; }    // ascending j: strict < keeps first
        }
        gv[g]=nv; gj[g]=nj;
      }
    }
    float lv = gv[0]; int lj = gj[0];
    #pragma unroll
    for (int g=1; g<NG; g++)
      if (gv[g]<lv || (gv[g]==lv && gj[g]<lj)){ lv=gv[g]; lj=gj[g]; }
    float rd = lv; int rj = lj;
    dppmin_fj<0x111>(rd,rj);
    dppmin_fj<0x112>(rd,rj);
    dppmin_fj<0x114>(rd,rj);
    dppmin_fj<0x118>(rd,rj);
    dppmin_fj<0x142>(rd,rj);
    dppmin_fj<0x143>(rd,rj);                   // lane63 = global lex-min
    int wj = __builtin_amdgcn_readlane(rj,63); // wave-uniform winner
    if (lane == r) myout = wj;
    if ((wj & 63) == lane) exmask |= (1ull << (wj>>6));   // exact exclusion
    dirtyg = (wj>>6)/GS;
  }
  if (lane<16) idx_out[((size_t)b*Nq+q)*16 + lane] = myout;
}

// ------ fused: FPS (blocks 0..7) + layer-1 KNN (8..8199) + layer-1 GEMM
// (8200..8711). GEMM-1 reads ONLY pre-dispatch data (x, w_in/b_in, wl/wq
// from the earlier k_wt_all) and its yk/yq output is consumed by k_gather
// which launches after this dispatch — stream order, no new sync. The
// gemm blocks fill the idle CUs during the 1.7ms FPS serial chain.
__global__ __launch_bounds__(256) void k_fps_knn1(
    const float* __restrict__ coords0,
    int* __restrict__ idx1, int* __restrict__ idx2, int* __restrict__ idx3,
    float* __restrict__ c1, float* __restrict__ c2, float* __restrict__ c3,
    float* __restrict__ out, int* __restrict__ knn1,
    const float* __restrict__ w_in, const float* __restrict__ b_in,
    const float* __restrict__ wl1, const float* __restrict__ wq1,
    float* __restrict__ yk, float* __restrict__ yq)
{
  __shared__ float s1x[4096], s1y[4096], s1z[4096];  // 48 KB stage-1 copy
  __shared__ float s2x[2048], s2y[2048], s2z[2048];  // 24 KB staging
  __shared__ float s3x[512],  s3y[512],  s3z[512];   //  6 KB
  __shared__ float s4x[128],  s4y[128],  s4z[128];   //  1.5 KB
  __shared__ int   ssel[2048];                       //  8 KB (flushed at stage end)
  __shared__ alignas(32) ull mK[8];                  //  self-tagged merge slots
  if (blockIdx.x >= 8 + 8192){
    // ---- layer-1 dual GEMM, MODE-0 conv staging (r11-verified body,
    //      C=8 / O=32 / rowsPB=64 compile-time). sf overlays s1x.
    const int g = blockIdx.x - 8200;                 // 0..511
    const int b = g >> 6, bx = g & 63;
    const int tid = threadIdx.x;
    float* sf = s1x;                                 // 576 floats used
    const float* xb = coords0 + (size_t)b*4096*3;
    const int row0 = bx*64;
    for (int i=tid; i<64*8; i+=256){
      int r = i >> 3, c = i & 7;
      int row = row0 + r;
      float cx=xb[row*3], cy=xb[row*3+1], cz=xb[row*3+2];
      float s = __fadd_rn(__fadd_rn(__fmul_rn(cx,w_in[c*3+0]),
                                    __fmul_rn(cy,w_in[c*3+1])),
                          __fmul_rn(cz,w_in[c*3+2]));
      sf[r*9 + c] = __fadd_rn(s, b_in[c]);
    }
    __syncthreads();
    const int o = tid & 31, rg = tid >> 5;           // R=8
    float ak[8], aq[8];
    #pragma unroll
    for (int m=0;m<8;m++){ ak[m]=0.f; aq[m]=0.f; }
    const float* lp = wl1 + o;
    const float* qp = wq1 + o;
    const float* sfr = sf + rg*8*9;
    #pragma unroll
    for (int c=0;c<8;c++){
      float wl = lp[c*32];
      float wq = qp[c*32];
      #pragma unroll
      for (int m=0;m<8;m++){
        float xv = sfr[m*9 + c];
        ak[m] = fmaf(xv, wl, ak[m]);
        aq[m] = fmaf(xv, wq, aq[m]);
      }
    }
    size_t obase = ((size_t)b*4096 + row0 + rg*8)*32 + o;
    #pragma unroll
    for (int m=0;m<8;m++){
      yk[obase + (size_t)m*32] = ak[m];
      yq[obase + (size_t)m*32] = aq[m];
    }
    return;
  }
  if (blockIdx.x >= 8){
    int flat = blockIdx.x - 8;                       // 1024 blocks per batch
    int b = flat >> 10, qb = flat & 1023;
    int q = qb*4 + (threadIdx.x>>6);                 // 4 waves -> 4 queries
    knn_wave<64>(coords0, 4096, coords0, 4096, knn1, b, q, threadIdx.x&63);
    return;
  }
  const int b = blockIdx.x, tid = threadIdx.x;
  __builtin_amdgcn_s_setprio(3);                     // protect FPS issue slots
  const float* cb = coords0 + (size_t)b*4096*3;
  if (tid<8) mK[tid] = ~0ull;                        // tag 0xFFF (never valid)
  { // stage 1: 4096 -> 2048   (P=16, j = tid + p*256, coords -> regs + LDS)
    f32x2 px[8], py[8], pz[8];
    #pragma unroll
    for (int i=0;i<8;i++){
      int j0 = tid + ((2*i)<<8), j1 = tid + ((2*i+1)<<8);
      float X0=cb[3*j0], Y0=cb[3*j0+1], Z0=cb[3*j0+2];
      float X1=cb[3*j1], Y1=cb[3*j1+1], Z1=cb[3*j1+2];
      px[i].x=X0; px[i].y=X1; py[i].x=Y0; py[i].y=Y1; pz[i].x=Z0; pz[i].y=Z1;
      s1x[j0]=X0; s1y[j0]=Y0; s1z[j0]=Z0;
      s1x[j1]=X1; s1y[j1]=Y1; s1z[j1]=Z1;
    }
    float sx=cb[0], sy=cb[1], sz=cb[2];
    __syncthreads();
    fps_stage<16>(px,py,pz, 2048, sx,sy,sz, s1x,s1y,s1z,
                  mK, ssel, s2x,s2y,s2z, tid);
  }
  __syncthreads();                 // all waves out of stage-1 polls
  { // flush stage 1 (parallel): idx1 from ssel, c1 from staging
    float* c1b = c1 + (size_t)b*2048*3;
    for (int i=tid;i<2048;i+=256){
      idx1[b*2048+i]=ssel[i];
      c1b[3*i]=s2x[i]; c1b[3*i+1]=s2y[i]; c1b[3*i+2]=s2z[i];
    }
  }
  { // stage 2: 2048 -> 512    (P=8, coords from staging LDS)
    f32x2 px[4], py[4], pz[4];
    #pragma unroll
    for (int i=0;i<4;i++){
      int j0 = tid + ((2*i)<<8), j1 = tid + ((2*i+1)<<8);
      px[i].x=s2x[j0]; px[i].y=s2x[j1];
      py[i].x=s2y[j0]; py[i].y=s2y[j1];
      pz[i].x=s2z[j0]; pz[i].y=s2z[j1];
    }
    float sx=s2x[0], sy=s2y[0], sz=s2z[0];
    __syncthreads();                 // ssel flush done before rewrite
    fps_stage<8>(px,py,pz, 512, sx,sy,sz, s2x,s2y,s2z,
                 mK, ssel, s3x,s3y,s3z, tid);
  }
  __syncthreads();                 // all waves out of stage-2 polls
  {
    float* c2b = c2 + (size_t)b*512*3;
    for (int i=tid;i<512;i+=256){
      idx2[b*512+i]=ssel[i];
      c2b[3*i]=s3x[i]; c2b[3*i+1]=s3y[i]; c2b[3*i+2]=s3z[i];
    }
  }
  { // stage 3: 512 -> 128     (P=2)
    f32x2 px[1], py[1], pz[1];
    {
      int j0 = tid, j1 = tid + 256;
      px[0].x=s3x[j0]; px[0].y=s3x[j1];
      py[0].x=s3y[j0]; py[0].y=s3y[j1];
      pz[0].x=s3z[j0]; pz[0].y=s3z[j1];
    }
    float sx=s3x[0], sy=s3y[0], sz=s3z[0];
    __syncthreads();
    fps_stage<2>(px,py,pz, 128, sx,sy,sz, s3x,s3y,s3z,
                 mK, ssel, s4x,s4y,s4z, tid);
  }
  __syncthreads();
  {
    float* c3b = c3 + (size_t)b*128*3;
    float* ob  = out + (size_t)b*128*3;
    for (int i=tid;i<128;i+=256){
      idx3[b*128+i]=ssel[i];
      float X=s4x[i],Y=s4y[i],Z=s4z[i];
      c3b[3*i]=X; c3b[3*i+1]=Y; c3b[3*i+2]=Z;
      ob[3*i]=X; ob[3*i+1]=Y; ob[3*i+2]=Z;
    }
  }
}

// --------------- weight split+transpose (all 6 layers) + fused stats zero
struct WtParams {
  const float* W[6];
  float* wl[6];
  float* wq[6];
  int O[6], C[6], OC[6];
};
__global__ void k_wt_all(WtParams p, float* __restrict__ stats){
  int s = blockIdx.y;
  int t = blockIdx.x*blockDim.x + threadIdx.x;
  if (s==0 && t<384) stats[t] = 0.f;           // fused k_zero
  int OC = p.OC[s];
  if (t >= OC) return;
  int C = p.C[s], O = p.O[s];
  int o = t / C, c = t - o*C;
  const float* W = p.W[s];
  float wlv = W[o*2*C + c];
  float wrv = W[o*2*C + C + c];
  p.wl[s][c*O+o] = wlv;
  p.wq[s][c*O+o] = wrv - wlv;
}

// ---------------- fused per-layer: KNN (blocks 0..gknn-1) + dual GEMM (rest)
// (r11-verified) staging folds the producer transform (GN+leaky, layers 2+).
#define GEMM_M 8
template<int NPL>
__global__ __launch_bounds__(256,3) void k_knn_gemm(
    const float* __restrict__ cq, int Nq,
    const float* __restrict__ ck, int Nk, int* __restrict__ knnidx,
    const float* __restrict__ vmsrc,
    const float* __restrict__ stats, const float* __restrict__ gamma,
    const float* __restrict__ beta, float invcnt,
    int C, int O,
    const float* __restrict__ wlT, const float* __restrict__ wqT,
    float* __restrict__ yk, float* __restrict__ yq, int gknn)
{
  const int b = blockIdx.y;
  if ((int)blockIdx.x < gknn){
    int q = blockIdx.x*4 + (threadIdx.x>>6);
    if (q < Nq) knn_wave<NPL>(cq, Nq, ck, Nk, knnidx, b, q, threadIdx.x&63);
    return;
  }
  const int bx = blockIdx.x - gknn;
  extern __shared__ float sf[];                  // rowsPB x (C+1) padded tile
  const int o = threadIdx.x & (O-1);
  const int rg = threadIdx.x / O;
  const int R = blockDim.x / O;
  const int rowsPB = R*GEMM_M;
  const int row0 = bx * rowsPB;
  const int Cp = C+1;
  {
    const float* src = vmsrc + ((size_t)b*Nk + row0)*C;
    for (int i=threadIdx.x; i<rowsPB*C; i+=blockDim.x){
      int r = i / C, c = i - r*C;
      int g = (c*4)/C;
      float s1 = stats[b*8+g*2], s2 = stats[b*8+g*2+1];
      float mu = s1*invcnt;
      float var = fmaf(-mu,mu, s2*invcnt);
      float rs = 1.0f/sqrtf(var+1e-5f);
      float v = (src[i]-mu)*rs*gamma[c] + beta[c];
      sf[r*Cp + c] = (v>=0.f)? v : 0.2f*v;
    }
  }
  __syncthreads();
  float ak[GEMM_M], aq[GEMM_M];
  #pragma unroll
  for (int m=0;m<GEMM_M;m++){ ak[m]=0.f; aq[m]=0.f; }
  const float* lp = wlT + o;
  const float* qp = wqT + o;
  const float* sfr = sf + rg*GEMM_M*Cp;
  for (int c=0;c<C;c++){
    float wl = lp[(size_t)c*O];
    float wq = qp[(size_t)c*O];
    #pragma unroll
    for (int m=0;m<GEMM_M;m++){
      float xv = sfr[m*Cp + c];
      ak[m] = fmaf(xv, wl, ak[m]);
      aq[m] = fmaf(xv, wq, aq[m]);
    }
  }
  size_t obase = ((size_t)b*Nk + row0 + rg*GEMM_M)*O + o;
  #pragma unroll
  for (int m=0;m<GEMM_M;m++){
    yk[obase + (size_t)m*O] = ak[m];
    yq[obase + (size_t)m*O] = aq[m];
  }
}

// ---------------------------------- gather neighbors + max_k + GN statistics
__global__ void k_gather(const float* __restrict__ yk, const float* __restrict__ yq,
                         const int* __restrict__ knnidx, const int* __restrict__ qmap,
                         int Nq, int Nk, int O,
                         float* __restrict__ vmax, float* __restrict__ stats)
{
  const int b = blockIdx.y;
  const int o = threadIdx.x & (O-1);
  const int rg = threadIdx.x / O;
  const int R = blockDim.x / O;
  float ls=0.f, ls2=0.f;
  const float* ykb = yk + (size_t)b*Nk*O;
  const float* yqb = yq + (size_t)b*Nk*O;
  for (int nq = blockIdx.x*R + rg; nq < Nq; nq += gridDim.x*R){
    int qj = qmap ? qmap[b*Nq+nq] : nq;
    float vq = yqb[(size_t)qj*O + o];
    const int* ip = knnidx + ((size_t)b*Nq+nq)*16;
    float vmx = -3.4e38f;
    #pragma unroll
    for (int k=0;k<16;k++){
      int j = ip[k];
      float v = ykb[(size_t)j*O+o] + vq;
      vmx = fmaxf(vmx, v);
      ls += v; ls2 = fmaf(v,v,ls2);
    }
    vmax[((size_t)b*Nq+nq)*O+o] = vmx;
  }
  int span = O/4; if (span>64) span=64;          // group-aligned lane segments
  for (int mm=1; mm<span; mm<<=1){
    ls  += __shfl_xor(ls, mm);
    ls2 += __shfl_xor(ls2, mm);
  }
  __shared__ float sred[8];
  if (threadIdx.x<8) sred[threadIdx.x]=0.f;
  __syncthreads();
  int lane = threadIdx.x & 63;
  if ((lane & (span-1))==0){
    int g = (o*4)/O;
    atomicAdd(&sred[g*2+0], ls);
    atomicAdd(&sred[g*2+1], ls2);
  }
  __syncthreads();
  if (threadIdx.x<8) atomicAdd(&stats[b*8+threadIdx.x], sred[threadIdx.x]);
}

// ---------------------------------------------- GN normalize + leaky (on max)
// Only needed for the FINAL layer (7) whose output goes to d_out.
__global__ void k_norm(const float* __restrict__ vmax, const float* __restrict__ stats,
                       const float* __restrict__ gamma,
                       const float* __restrict__ beta,
                       int Nq, int O, float invcnt, float* __restrict__ outf)
{
  const int b = blockIdx.y;
  const int n = Nq*O;
  for (int i = blockIdx.x*blockDim.x+threadIdx.x; i<n; i+=gridDim.x*blockDim.x){
    int o = i & (O-1);
    int g = (o*4)/O;
    float s1 = stats[b*8+g*2], s2 = stats[b*8+g*2+1];
    float mu = s1*invcnt;
    float var = fmaf(-mu,mu, s2*invcnt);
    float rs = 1.0f/sqrtf(var+1e-5f);
    float v = (vmax[(size_t)b*n + i]-mu)*rs*gamma[o] + beta[o];
    outf[(size_t)b*n + i] = (v>=0.f)? v : 0.2f*v;
  }
}

// ===========================================================================
extern "C" void kernel_launch(void* const* d_in, const int* in_sizes, int n_in,
                              void* d_out, int out_size, void* d_ws, size_t ws_size,
                              hipStream_t stream)
{
  const int B = 8;
  const float* x    = (const float*)d_in[0];
  const float* w_in = (const float*)d_in[4];
  const float* b_in = (const float*)d_in[5];
  const float *Wm[6], *Gm[6], *Bm[6];
  for (int i=0;i<6;i++){
    Wm[i]=(const float*)d_in[6+3*i];
    Gm[i]=(const float*)d_in[6+3*i+1];
    Bm[i]=(const float*)d_in[6+3*i+2];
  }
  float* ws = (float*)d_ws;
  float* out = (float*)d_out;
  const size_t OFF_C1=4030464,  OFF_C2=4079616, OFF_C3=4091904,
               OFF_YK=4094976,  OFF_YQ=6192128, OFF_VM=8289280,
               OFF_WL=9337856,  OFF_WQ=9468928, OFF_ST=9600000,
               OFF_I1=9600384,  OFF_I2=9616768, OFF_I3=9620864, OFF_KNN=9621888,
               TOTAL=10146176;  // ~40.6 MB
  if (ws_size < TOTAL*sizeof(float)) return;
  float *c1=ws+OFF_C1, *c2=ws+OFF_C2, *c3=ws+OFF_C3,
        *yk=ws+OFF_YK, *yq=ws+OFF_YQ, *vm=ws+OFF_VM, *stats=ws+OFF_ST;
  int *i1=(int*)(ws+OFF_I1), *i2=(int*)(ws+OFF_I2), *i3=(int*)(ws+OFF_I3),
      *knn=(int*)(ws+OFF_KNN);

  const int OCs[6]  = {256, 2048, 8192, 16384, 32768, 65536};
  const int OCoff[6]= {0,   256,  2304, 10496, 26880, 59648};

  struct St { int C,O,Nk,Nq; const float* cq; const float* ck;
              const int* qmap; };
  const St st[6] = {
    {8,   32, 4096, 4096, x,  x,  nullptr},   // layer 1 (gemm fused in FPS disp)
    {32,  64, 4096, 2048, c1, x,  i1},        // layer 2
    {64, 128, 2048,  512, c2, c1, i2},        // layer 4
    {128,128,  512,  512, c2, c2, nullptr},   // layer 5
    {128,256,  512,  128, c3, c2, i3},        // layer 6
    {256,256,  128,  128, c3, c3, nullptr},   // layer 7
  };
  float invc[6];
  for (int s=0;s<6;s++)
    invc[s] = 1.0f / ((float)(st[s].O/4) * (float)st[s].Nq * 16.0f);

  WtParams wp;
  for (int s=0;s<6;s++){
    wp.W[s]=Wm[s];
    wp.wl[s]=ws+OFF_WL+OCoff[s];
    wp.wq[s]=ws+OFF_WQ+OCoff[s];
    wp.O[s]=st[s].O; wp.C[s]=st[s].C; wp.OC[s]=OCs[s];
  }
  k_wt_all<<<dim3(256,6), 256, 0, stream>>>(wp, stats);

  // FPS (0..7) + layer-1 KNN (8..8199) + layer-1 GEMM (8200..8711)
  k_fps_knn1<<<8 + 8*1024 + 512, 256, 0, stream>>>(x, i1, i2, i3, c1, c2, c3,
                                                   out, knn,
                                                   w_in, b_in,
                                                   ws+OFF_WL, ws+OFF_WQ,
                                                   yk, yq);

  for (int s=0;s<6;s++){
    const St& S = st[s];
    if (s > 0){
      int rowsPB = 2048 / S.O;                       // (256/O)*GEMM_M
      int ggemm = S.Nk / rowsPB;
      int gknn  = (S.Nq + 3)/4;
      dim3 gg(gknn + ggemm, B);
      size_t shb = (size_t)rowsPB * (S.C+1) * sizeof(float);
      const float* wl = ws+OFF_WL+OCoff[s];
      const float* wqp = ws+OFF_WQ+OCoff[s];
      const float* stp = stats + (s-1)*64;
      const float* gp  = Gm[s-1];
      const float* bp  = Bm[s-1];
      float ivc = invc[s-1];
      int npl = S.Nk >> 6;           // 64, 32, 8, 2
      if      (npl == 64)
        k_knn_gemm<64><<<gg, 256, shb, stream>>>(S.cq,S.Nq,S.ck,S.Nk,knn,
          vm, stp, gp, bp, ivc, S.C, S.O, wl, wqp, yk, yq, gknn);
      else if (npl == 32)
        k_knn_gemm<32><<<gg, 256, shb, stream>>>(S.cq,S.Nq,S.ck,S.Nk,knn,
          vm, stp, gp, bp, ivc, S.C, S.O, wl, wqp, yk, yq, gknn);
      else if (npl ==  8)
        k_knn_gemm< 8><<<gg, 256, shb, stream>>>(S.cq,S.Nq,S.ck,S.Nk,knn,
          vm, stp, gp, bp, ivc, S.C, S.O, wl, wqp, yk, yq, gknn);
      else
        k_knn_gemm< 2><<<gg, 256, shb, stream>>>(S.cq,S.Nq,S.ck,S.Nk,knn,
          vm, stp, gp, bp, ivc, S.C, S.O, wl, wqp, yk, yq, gknn);
    }
    dim3 gs(64, B);
    k_gather<<<gs, 256, 0, stream>>>(yk, yq, knn, S.qmap, S.Nq, S.Nk, S.O,
                                     vm, stats + s*64);
  }
  // final layer's GN+leaky -> d_out features
  {
    dim3 gn((128*256 + 255)/256, B);
    k_norm<<<gn, 256, 0, stream>>>(vm, stats + 5*64, Gm[5], Bm[5],
                                   128, 256, invc[5], out + 8*128*3);
  }
}

// Round 14
// 2131.989 us; speedup vs baseline: 2.5725x; 1.0752x over previous
//
#include <hip/hip_runtime.h>
#include <hip/hip_bf16.h>
#include <math.h>

#define DEVI __device__ __forceinline__
typedef unsigned long long ull;
typedef float f32x2 __attribute__((ext_vector_type(2)));

// ---------------------------------------------------------------- FPS
// r8/r11-VERIFIED 4-wave path (FROZEN — r4..r12 established the exchange
// floor): packed passA, fused DPP max chain + min-index chain, self-tagged
// u64 key, batched plain-load poll, coords from LDS point copy.
DEVI f32x2 pk_sub(f32x2 a, f32x2 b){
  f32x2 r;
  asm("v_pk_add_f32 %0, %1, %2 neg_lo:[0,1] neg_hi:[0,1]" : "=v"(r) : "v"(a), "v"(b));
  return r;
}
DEVI f32x2 pk_mul(f32x2 a, f32x2 b){
  f32x2 r; asm("v_pk_mul_f32 %0, %1, %2" : "=v"(r) : "v"(a), "v"(b)); return r;
}
DEVI f32x2 pk_add(f32x2 a, f32x2 b){
  f32x2 r; asm("v_pk_add_f32 %0, %1, %2" : "=v"(r) : "v"(a), "v"(b)); return r;
}

template<int CTRL>
DEVI float dppmaxf(float x){
  float o = __int_as_float(__builtin_amdgcn_update_dpp(__float_as_int(x),__float_as_int(x),CTRL,0xF,0xF,false));
  return fmaxf(x,o);
}
template<int CTRL>
DEVI unsigned dppminu(unsigned x){
  unsigned o = (unsigned)__builtin_amdgcn_update_dpp((int)x,(int)x,CTRL,0xF,0xF,false);
  return (x < o) ? x : o;
}

// ------- 4-wave stage (r8-verified)
template<int P>
DEVI void fps_stage(f32x2 (&px)[P/2], f32x2 (&py)[P/2], f32x2 (&pz)[P/2],
                    int m, float sx, float sy, float sz,
                    const float* cpx, const float* cpy, const float* cpz,
                    ull* mK,                      // [2][4] flattened, plain LDS
                    int* ssel, float* snx, float* sny, float* snz, int tid)
{
  const int wv = tid>>6, lane = tid&63;
  float dist[P];
  #pragma unroll
  for (int p=0;p<P;p++) dist[p]=1e10f;
  if (tid==0){ ssel[0]=0; if (snx){ snx[0]=sx; sny[0]=sy; snz[0]=sz; } }
  #pragma unroll 1
  for (int it=1; it<m; it++){
    f32x2 vsx, vsy, vsz;
    vsx.x=sx; vsx.y=sx; vsy.x=sy; vsy.y=sy; vsz.x=sz; vsz.y=sz;
    float bv = -1.f;
    #pragma unroll
    for (int i=0;i<P/2;i++){
      f32x2 dx = pk_sub(px[i], vsx);
      f32x2 dy = pk_sub(py[i], vsy);
      f32x2 dz = pk_sub(pz[i], vsz);
      f32x2 s  = pk_add(pk_add(pk_mul(dx,dx), pk_mul(dy,dy)), pk_mul(dz,dz));
      float d0 = fminf(dist[2*i],   s.x);
      float d1 = fminf(dist[2*i+1], s.y);
      dist[2*i] = d0; dist[2*i+1] = d1;
      bv = fmaxf(bv, d0);
      bv = fmaxf(bv, d1);
    }
    int bidx = 0;
    #pragma unroll
    for (int p=P-1;p>=0;p--) if (dist[p]==bv) bidx = tid+(p<<8);
    float w = bv;
    w = dppmaxf<0x111>(w);
    w = dppmaxf<0x112>(w);
    w = dppmaxf<0x114>(w);
    w = dppmaxf<0x118>(w);
    w = dppmaxf<0x142>(w);
    w = dppmaxf<0x143>(w);   // lane63 = wave max
    float bvw = __uint_as_float((unsigned)__builtin_amdgcn_readlane(__float_as_int(w),63));
    unsigned cand = (bv == bvw) ? (unsigned)bidx : 0xFFFFFFFFu;
    cand = dppminu<0x111>(cand);
    cand = dppminu<0x112>(cand);
    cand = dppminu<0x114>(cand);
    cand = dppminu<0x118>(cand);
    cand = dppminu<0x142>(cand);
    cand = dppminu<0x143>(cand);               // lane63 = wave-min match idx
    const unsigned itu = (unsigned)it;
    ull* slot = mK + ((it&1)<<2);
    if (lane==63){
      unsigned lo = ((~cand & 0xFFFu)<<12) | itu;       // r6-verified encoding
      *(volatile ull*)(slot + wv) = ((ull)__float_as_uint(bvw)<<32) | (ull)lo;
    }
    ull k0,k1,k2,k3;
    for (;;){
      asm volatile("" ::: "memory");     // force re-read, allow batching
      k0=slot[0]; k1=slot[1]; k2=slot[2]; k3=slot[3];
      unsigned chk = (((unsigned)k0 ^ itu) | ((unsigned)k1 ^ itu) |
                      ((unsigned)k2 ^ itu) | ((unsigned)k3 ^ itu)) & 0xFFFu;
      if (chk == 0u) break;
    }
    ull ka = (k1>k0)?k1:k0;
    ull kb = (k3>k2)?k3:k2;
    ull kw = (kb>ka)?kb:ka;
    int gi = (int)((~((unsigned)(kw & 0xffffffffull) >> 12)) & 0xFFFu);
    sx = cpx[gi]; sy = cpy[gi]; sz = cpz[gi];   // LDS broadcast reads
    if (tid==0){
      ssel[it]=gi;
      if (snx){ snx[it]=sx; sny[it]=sy; snz[it]=sz; }
    }
  }
}

// ----------------------------------------- KNN wave body (one wave = one q)
// (r3/r4/r6-verified) Scratch-free top-16 with EXACT bitmask exclusion.
template<int CTRL>
DEVI void dppmin_fj(float& d, int& j){
  float od = __int_as_float(__builtin_amdgcn_update_dpp(__float_as_int(d),__float_as_int(d),CTRL,0xF,0xF,false));
  int   oj = __builtin_amdgcn_update_dpp(j,j,CTRL,0xF,0xF,false);
  bool tk = (od < d) || (od == d && oj < j);
  d = tk?od:d; j = tk?oj:j;
}

DEVI float dist_qk(const float* __restrict__ ckb, int j,
                   float qx, float qy, float qz, float sqq){
  float kx=ckb[3*j], ky=ckb[3*j+1], kz=ckb[3*j+2];
  float sk  = __fadd_rn(__fadd_rn(__fmul_rn(kx,kx),__fmul_rn(ky,ky)),
                        __fmul_rn(kz,kz));
  float dot = __fadd_rn(__fadd_rn(__fmul_rn(qx,kx),__fmul_rn(qy,ky)),
                        __fmul_rn(qz,kz));
  return __fadd_rn(__fsub_rn(sqq, __fmul_rn(2.0f,dot)), sk);
}

template<int NPL>   // points per lane = Nk/64; NPL in {64,32,8,2}
DEVI void knn_wave(const float* __restrict__ cq, int Nq,
                   const float* __restrict__ ck, int Nk,
                   int* __restrict__ idx_out, int b, int q, int lane)
{
  size_t r3 = ((size_t)b*Nq+q)*3;
  float qx=cq[r3], qy=cq[r3+1], qz=cq[r3+2];
  float sqq = __fadd_rn(__fadd_rn(__fmul_rn(qx,qx),__fmul_rn(qy,qy)),
                        __fmul_rn(qz,qz));
  constexpr int GS = (NPL < 8) ? NPL : 8;
  constexpr int NG = NPL / GS;
  float gv[NG]; int gj[NG];
  const float* ckb = ck + (size_t)b*Nk*3;
  ull exmask = 0;                 // bit i: this lane's element i extracted
  int dirtyg = -1;                // -1 => rebuild all groups (round 0)
  int myout = 0;
  #pragma unroll 1
  for (int r=0; r<16; r++){
    #pragma unroll
    for (int g=0; g<NG; g++){
      if (dirtyg < 0 || dirtyg == g){          // wave-uniform branch
        float nv=__int_as_float(0x7f800000); int nj=0x7fffffff;
        #pragma unroll
        for (int e=0; e<GS; e++){
          const int i = g*GS+e;                // compile-time bit index
          int j = lane + (i<<6);
          float d = dist_qk(ckb, j, qx,qy,qz, sqq);
          bool rem = ((exmask >> i) & 1ull) == 0ull;
          if (rem && d < nv){ nv=d; nj=j; }    // ascending j: strict < keeps first
        }
        gv[g]=nv; gj[g]=nj;
      }
    }
    float lv = gv[0]; int lj = gj[0];
    #pragma unroll
    for (int g=1; g<NG; g++)
      if (gv[g]<lv || (gv[g]==lv && gj[g]<lj)){ lv=gv[g]; lj=gj[g]; }
    float rd = lv; int rj = lj;
    dppmin_fj<0x111>(rd,rj);
    dppmin_fj<0x112>(rd,rj);
    dppmin_fj<0x114>(rd,rj);
    dppmin_fj<0x118>(rd,rj);
    dppmin_fj<0x142>(rd,rj);
    dppmin_fj<0x143>(rd,rj);                   // lane63 = global lex-min
    int wj = __builtin_amdgcn_readlane(rj,63); // wave-uniform winner
    if (lane == r) myout = wj;
    if ((wj & 63) == lane) exmask |= (1ull << (wj>>6));   // exact exclusion
    dirtyg = (wj>>6)/GS;
  }
  if (lane<16) idx_out[((size_t)b*Nq+q)*16 + lane] = myout;
}

// ------------------------------- gather body (shared: kernel + fused blocks)
DEVI void gather_dev(const float* __restrict__ yk, const float* __restrict__ yq,
                     const int* __restrict__ knnidx, const int* __restrict__ qmap,
                     int Nq, int Nk, int O, int b, int bx, int gX,
                     float* __restrict__ vmax, float* __restrict__ stats,
                     float* sred, int tidx)
{
  const int o = tidx & (O-1);
  const int rg = tidx / O;
  const int R = 256 / O;
  float ls=0.f, ls2=0.f;
  const float* ykb = yk + (size_t)b*Nk*O;
  const float* yqb = yq + (size_t)b*Nk*O;
  for (int nq = bx*R + rg; nq < Nq; nq += gX*R){
    int qj = qmap ? qmap[b*Nq+nq] : nq;
    float vq = yqb[(size_t)qj*O + o];
    const int* ip = knnidx + ((size_t)b*Nq+nq)*16;
    float vmx = -3.4e38f;
    #pragma unroll
    for (int k=0;k<16;k++){
      int j = ip[k];
      float v = ykb[(size_t)j*O+o] + vq;
      vmx = fmaxf(vmx, v);
      ls += v; ls2 = fmaf(v,v,ls2);
    }
    vmax[((size_t)b*Nq+nq)*O+o] = vmx;
  }
  int span = O/4; if (span>64) span=64;          // group-aligned lane segments
  for (int mm=1; mm<span; mm<<=1){
    ls  += __shfl_xor(ls, mm);
    ls2 += __shfl_xor(ls2, mm);
  }
  if (tidx<8) sred[tidx]=0.f;
  __syncthreads();
  int lane = tidx & 63;
  if ((lane & (span-1))==0){
    int g = (o*4)/O;
    atomicAdd(&sred[g*2+0], ls);
    atomicAdd(&sred[g*2+1], ls2);
  }
  __syncthreads();
  if (tidx<8) atomicAdd(&stats[b*8+tidx], sred[tidx]);
}

// ------ D1: FPS stage 1 (blocks 0..7) + layer-1 KNN (8..8199) + layer-1
// GEMM (8200..8711). (r13-verified bodies; stages 2/3 moved to D2.)
__global__ __launch_bounds__(256) void k_fps1(
    const float* __restrict__ coords0,
    int* __restrict__ idx1, float* __restrict__ c1, int* __restrict__ knn1,
    const float* __restrict__ w_in, const float* __restrict__ b_in,
    const float* __restrict__ wl1, const float* __restrict__ wq1,
    float* __restrict__ yk, float* __restrict__ yq)
{
  __shared__ float s1x[4096], s1y[4096], s1z[4096];  // 48 KB stage-1 copy
  __shared__ float s2x[2048], s2y[2048], s2z[2048];  // 24 KB staging
  __shared__ int   ssel[2048];                       //  8 KB
  __shared__ alignas(32) ull mK[8];                  //  self-tagged merge slots
  if (blockIdx.x >= 8 + 8192){
    // ---- layer-1 dual GEMM, MODE-0 conv staging (r13-verified)
    const int g = blockIdx.x - 8200;                 // 0..511
    const int b = g >> 6, bx = g & 63;
    const int tid = threadIdx.x;
    float* sf = s1x;                                 // 576 floats used
    const float* xb = coords0 + (size_t)b*4096*3;
    const int row0 = bx*64;
    for (int i=tid; i<64*8; i+=256){
      int r = i >> 3, c = i & 7;
      int row = row0 + r;
      float cx=xb[row*3], cy=xb[row*3+1], cz=xb[row*3+2];
      float s = __fadd_rn(__fadd_rn(__fmul_rn(cx,w_in[c*3+0]),
                                    __fmul_rn(cy,w_in[c*3+1])),
                          __fmul_rn(cz,w_in[c*3+2]));
      sf[r*9 + c] = __fadd_rn(s, b_in[c]);
    }
    __syncthreads();
    const int o = tid & 31, rg = tid >> 5;           // R=8
    float ak[8], aq[8];
    #pragma unroll
    for (int m=0;m<8;m++){ ak[m]=0.f; aq[m]=0.f; }
    const float* lp = wl1 + o;
    const float* qp = wq1 + o;
    const float* sfr = sf + rg*8*9;
    #pragma unroll
    for (int c=0;c<8;c++){
      float wl = lp[c*32];
      float wq = qp[c*32];
      #pragma unroll
      for (int m=0;m<8;m++){
        float xv = sfr[m*9 + c];
        ak[m] = fmaf(xv, wl, ak[m]);
        aq[m] = fmaf(xv, wq, aq[m]);
      }
    }
    size_t obase = ((size_t)b*4096 + row0 + rg*8)*32 + o;
    #pragma unroll
    for (int m=0;m<8;m++){
      yk[obase + (size_t)m*32] = ak[m];
      yq[obase + (size_t)m*32] = aq[m];
    }
    return;
  }
  if (blockIdx.x >= 8){
    int flat = blockIdx.x - 8;                       // 1024 blocks per batch
    int b = flat >> 10, qb = flat & 1023;
    int q = qb*4 + (threadIdx.x>>6);                 // 4 waves -> 4 queries
    knn_wave<64>(coords0, 4096, coords0, 4096, knn1, b, q, threadIdx.x&63);
    return;
  }
  const int b = blockIdx.x, tid = threadIdx.x;
  __builtin_amdgcn_s_setprio(3);                     // protect FPS issue slots
  const float* cb = coords0 + (size_t)b*4096*3;
  if (tid<8) mK[tid] = ~0ull;                        // tag 0xFFF (never valid)
  { // stage 1: 4096 -> 2048   (P=16, j = tid + p*256, coords -> regs + LDS)
    f32x2 px[8], py[8], pz[8];
    #pragma unroll
    for (int i=0;i<8;i++){
      int j0 = tid + ((2*i)<<8), j1 = tid + ((2*i+1)<<8);
      float X0=cb[3*j0], Y0=cb[3*j0+1], Z0=cb[3*j0+2];
      float X1=cb[3*j1], Y1=cb[3*j1+1], Z1=cb[3*j1+2];
      px[i].x=X0; px[i].y=X1; py[i].x=Y0; py[i].y=Y1; pz[i].x=Z0; pz[i].y=Z1;
      s1x[j0]=X0; s1y[j0]=Y0; s1z[j0]=Z0;
      s1x[j1]=X1; s1y[j1]=Y1; s1z[j1]=Z1;
    }
    float sx=cb[0], sy=cb[1], sz=cb[2];
    __syncthreads();
    fps_stage<16>(px,py,pz, 2048, sx,sy,sz, s1x,s1y,s1z,
                  mK, ssel, s2x,s2y,s2z, tid);
  }
  __syncthreads();                 // all waves out of stage-1 polls
  { // flush stage 1: idx1 from ssel, c1 from staging (read by D2)
    float* c1b = c1 + (size_t)b*2048*3;
    for (int i=tid;i<2048;i+=256){
      idx1[b*2048+i]=ssel[i];
      c1b[3*i]=s2x[i]; c1b[3*i+1]=s2y[i]; c1b[3*i+2]=s2z[i];
    }
  }
}

// ------ D2: FPS stages 2+3 (blocks 0..7, reload from c1 — bit-identical to
// the s2 staging it was flushed from) + layer-1 GATHER (8..519) + layer-2
// KNN (520..4615). Gather/knn inputs are all D1-complete; knn-2 writes a
// SEPARATE knn2 buffer (gather-1 concurrently reads knn-1 from knn).
__global__ __launch_bounds__(256) void k_fps23(
    const float* __restrict__ coords0, const float* __restrict__ c1,
    int* __restrict__ idx2, int* __restrict__ idx3,
    float* __restrict__ c2, float* __restrict__ c3,
    float* __restrict__ out,
    const float* __restrict__ yk, const float* __restrict__ yq,
    const int* __restrict__ knn1, float* __restrict__ vm,
    float* __restrict__ stats0, int* __restrict__ knn2)
{
  __shared__ float s2x[2048], s2y[2048], s2z[2048];  // 24 KB point copy
  __shared__ float s3x[512],  s3y[512],  s3z[512];   //  6 KB
  __shared__ float s4x[128],  s4y[128],  s4z[128];   //  1.5 KB
  __shared__ int   ssel[512];                        //  2 KB
  __shared__ alignas(32) ull mK[8];
  __shared__ float sred[8];
  if (blockIdx.x >= 520){
    int flat = blockIdx.x - 520;                     // 512 q-blocks per batch
    int b = flat >> 9, qb = flat & 511;
    int q = qb*4 + (threadIdx.x>>6);                 // q < 2048
    knn_wave<64>(c1, 2048, coords0, 4096, knn2, b, q, threadIdx.x&63);
    return;
  }
  if (blockIdx.x >= 8){
    int g = blockIdx.x - 8;                          // 0..511
    int b = g >> 6, bx = g & 63;
    gather_dev(yk, yq, knn1, nullptr, 4096, 4096, 32, b, bx, 64,
               vm, stats0, sred, threadIdx.x);
    return;
  }
  const int b = blockIdx.x, tid = threadIdx.x;
  __builtin_amdgcn_s_setprio(3);
  if (tid<8) mK[tid] = ~0ull;
  { // refill the stage-2 point copy from c1 (bit-identical to D1's staging)
    const float* c1b = c1 + (size_t)b*2048*3;
    for (int i=tid;i<2048;i+=256){
      s2x[i]=c1b[3*i]; s2y[i]=c1b[3*i+1]; s2z[i]=c1b[3*i+2];
    }
  }
  __syncthreads();
  { // stage 2: 2048 -> 512    (P=8, r13-verified)
    f32x2 px[4], py[4], pz[4];
    #pragma unroll
    for (int i=0;i<4;i++){
      int j0 = tid + ((2*i)<<8), j1 = tid + ((2*i+1)<<8);
      px[i].x=s2x[j0]; px[i].y=s2x[j1];
      py[i].x=s2y[j0]; py[i].y=s2y[j1];
      pz[i].x=s2z[j0]; pz[i].y=s2z[j1];
    }
    float sx=s2x[0], sy=s2y[0], sz=s2z[0];
    __syncthreads();
    fps_stage<8>(px,py,pz, 512, sx,sy,sz, s2x,s2y,s2z,
                 mK, ssel, s3x,s3y,s3z, tid);
  }
  __syncthreads();
  {
    float* c2b = c2 + (size_t)b*512*3;
    for (int i=tid;i<512;i+=256){
      idx2[b*512+i]=ssel[i];
      c2b[3*i]=s3x[i]; c2b[3*i+1]=s3y[i]; c2b[3*i+2]=s3z[i];
    }
  }
  __syncthreads();                 // flush reads done before ssel rewrite
  { // stage 3: 512 -> 128     (P=2, r13-verified)
    f32x2 px[1], py[1], pz[1];
    {
      int j0 = tid, j1 = tid + 256;
      px[0].x=s3x[j0]; px[0].y=s3x[j1];
      py[0].x=s3y[j0]; py[0].y=s3y[j1];
      pz[0].x=s3z[j0]; pz[0].y=s3z[j1];
    }
    float sx=s3x[0], sy=s3y[0], sz=s3z[0];
    __syncthreads();
    fps_stage<2>(px,py,pz, 128, sx,sy,sz, s3x,s3y,s3z,
                 mK, ssel, s4x,s4y,s4z, tid);
  }
  __syncthreads();
  {
    float* c3b = c3 + (size_t)b*128*3;
    float* ob  = out + (size_t)b*128*3;
    for (int i=tid;i<128;i+=256){
      idx3[b*128+i]=ssel[i];
      float X=s4x[i],Y=s4y[i],Z=s4z[i];
      c3b[3*i]=X; c3b[3*i+1]=Y; c3b[3*i+2]=Z;
      ob[3*i]=X; ob[3*i+1]=Y; ob[3*i+2]=Z;
    }
  }
}

// --------------- weight split+transpose (all 6 layers) + fused stats zero
struct WtParams {
  const float* W[6];
  float* wl[6];
  float* wq[6];
  int O[6], C[6], OC[6];
};
__global__ void k_wt_all(WtParams p, float* __restrict__ stats){
  int s = blockIdx.y;
  int t = blockIdx.x*blockDim.x + threadIdx.x;
  if (s==0 && t<384) stats[t] = 0.f;           // fused k_zero
  int OC = p.OC[s];
  if (t >= OC) return;
  int C = p.C[s], O = p.O[s];
  int o = t / C, c = t - o*C;
  const float* W = p.W[s];
  float wlv = W[o*2*C + c];
  float wrv = W[o*2*C + C + c];
  p.wl[s][c*O+o] = wlv;
  p.wq[s][c*O+o] = wrv - wlv;
}

// ---------------- fused per-layer: KNN (blocks 0..gknn-1) + dual GEMM (rest)
// (r11-verified) staging folds the producer transform (GN+leaky).
#define GEMM_M 8
template<int NPL>
__global__ __launch_bounds__(256,3) void k_knn_gemm(
    const float* __restrict__ cq, int Nq,
    const float* __restrict__ ck, int Nk, int* __restrict__ knnidx,
    const float* __restrict__ vmsrc,
    const float* __restrict__ stats, const float* __restrict__ gamma,
    const float* __restrict__ beta, float invcnt,
    int C, int O,
    const float* __restrict__ wlT, const float* __restrict__ wqT,
    float* __restrict__ yk, float* __restrict__ yq, int gknn)
{
  const int b = blockIdx.y;
  if ((int)blockIdx.x < gknn){
    int q = blockIdx.x*4 + (threadIdx.x>>6);
    if (q < Nq) knn_wave<NPL>(cq, Nq, ck, Nk, knnidx, b, q, threadIdx.x&63);
    return;
  }
  const int bx = blockIdx.x - gknn;
  extern __shared__ float sf[];                  // rowsPB x (C+1) padded tile
  const int o = threadIdx.x & (O-1);
  const int rg = threadIdx.x / O;
  const int R = blockDim.x / O;
  const int rowsPB = R*GEMM_M;
  const int row0 = bx * rowsPB;
  const int Cp = C+1;
  {
    const float* src = vmsrc + ((size_t)b*Nk + row0)*C;
    for (int i=threadIdx.x; i<rowsPB*C; i+=blockDim.x){
      int r = i / C, c = i - r*C;
      int g = (c*4)/C;
      float s1 = stats[b*8+g*2], s2 = stats[b*8+g*2+1];
      float mu = s1*invcnt;
      float var = fmaf(-mu,mu, s2*invcnt);
      float rs = 1.0f/sqrtf(var+1e-5f);
      float v = (src[i]-mu)*rs*gamma[c] + beta[c];
      sf[r*Cp + c] = (v>=0.f)? v : 0.2f*v;
    }
  }
  __syncthreads();
  float ak[GEMM_M], aq[GEMM_M];
  #pragma unroll
  for (int m=0;m<GEMM_M;m++){ ak[m]=0.f; aq[m]=0.f; }
  const float* lp = wlT + o;
  const float* qp = wqT + o;
  const float* sfr = sf + rg*GEMM_M*Cp;
  for (int c=0;c<C;c++){
    float wl = lp[(size_t)c*O];
    float wq = qp[(size_t)c*O];
    #pragma unroll
    for (int m=0;m<GEMM_M;m++){
      float xv = sfr[m*Cp + c];
      ak[m] = fmaf(xv, wl, ak[m]);
      aq[m] = fmaf(xv, wq, aq[m]);
    }
  }
  size_t obase = ((size_t)b*Nk + row0 + rg*GEMM_M)*O + o;
  #pragma unroll
  for (int m=0;m<GEMM_M;m++){
    yk[obase + (size_t)m*O] = ak[m];
    yq[obase + (size_t)m*O] = aq[m];
  }
}

// ---------------------------------- gather kernel (layers 2+)
__global__ void k_gather(const float* __restrict__ yk, const float* __restrict__ yq,
                         const int* __restrict__ knnidx, const int* __restrict__ qmap,
                         int Nq, int Nk, int O,
                         float* __restrict__ vmax, float* __restrict__ stats)
{
  __shared__ float sred[8];
  gather_dev(yk, yq, knnidx, qmap, Nq, Nk, O,
             blockIdx.y, blockIdx.x, gridDim.x, vmax, stats, sred, threadIdx.x);
}

// ---------------------------------------------- GN normalize + leaky (on max)
// Only needed for the FINAL layer (7) whose output goes to d_out.
__global__ void k_norm(const float* __restrict__ vmax, const float* __restrict__ stats,
                       const float* __restrict__ gamma,
                       const float* __restrict__ beta,
                       int Nq, int O, float invcnt, float* __restrict__ outf)
{
  const int b = blockIdx.y;
  const int n = Nq*O;
  for (int i = blockIdx.x*blockDim.x+threadIdx.x; i<n; i+=gridDim.x*blockDim.x){
    int o = i & (O-1);
    int g = (o*4)/O;
    float s1 = stats[b*8+g*2], s2 = stats[b*8+g*2+1];
    float mu = s1*invcnt;
    float var = fmaf(-mu,mu, s2*invcnt);
    float rs = 1.0f/sqrtf(var+1e-5f);
    float v = (vmax[(size_t)b*n + i]-mu)*rs*gamma[o] + beta[o];
    outf[(size_t)b*n + i] = (v>=0.f)? v : 0.2f*v;
  }
}

// ===========================================================================
extern "C" void kernel_launch(void* const* d_in, const int* in_sizes, int n_in,
                              void* d_out, int out_size, void* d_ws, size_t ws_size,
                              hipStream_t stream)
{
  const int B = 8;
  const float* x    = (const float*)d_in[0];
  const float* w_in = (const float*)d_in[4];
  const float* b_in = (const float*)d_in[5];
  const float *Wm[6], *Gm[6], *Bm[6];
  for (int i=0;i<6;i++){
    Wm[i]=(const float*)d_in[6+3*i];
    Gm[i]=(const float*)d_in[6+3*i+1];
    Bm[i]=(const float*)d_in[6+3*i+2];
  }
  float* ws = (float*)d_ws;
  float* out = (float*)d_out;
  const size_t OFF_KNN2=0,      // 262144 ints in the dead f-buffer region
               OFF_C1=4030464,  OFF_C2=4079616, OFF_C3=4091904,
               OFF_YK=4094976,  OFF_YQ=6192128, OFF_VM=8289280,
               OFF_WL=9337856,  OFF_WQ=9468928, OFF_ST=9600000,
               OFF_I1=9600384,  OFF_I2=9616768, OFF_I3=9620864, OFF_KNN=9621888,
               TOTAL=10146176;  // ~40.6 MB
  if (ws_size < TOTAL*sizeof(float)) return;
  float *c1=ws+OFF_C1, *c2=ws+OFF_C2, *c3=ws+OFF_C3,
        *yk=ws+OFF_YK, *yq=ws+OFF_YQ, *vm=ws+OFF_VM, *stats=ws+OFF_ST;
  int *i1=(int*)(ws+OFF_I1), *i2=(int*)(ws+OFF_I2), *i3=(int*)(ws+OFF_I3),
      *knn=(int*)(ws+OFF_KNN), *knn2=(int*)(ws+OFF_KNN2);

  const int OCs[6]  = {256, 2048, 8192, 16384, 32768, 65536};
  const int OCoff[6]= {0,   256,  2304, 10496, 26880, 59648};

  struct St { int C,O,Nk,Nq; const float* cq; const float* ck;
              const int* qmap; };
  const St st[6] = {
    {8,   32, 4096, 4096, x,  x,  nullptr},   // layer 1 (gemm+knn in D1)
    {32,  64, 4096, 2048, c1, x,  i1},        // layer 2 (knn in D2)
    {64, 128, 2048,  512, c2, c1, i2},        // layer 4
    {128,128,  512,  512, c2, c2, nullptr},   // layer 5
    {128,256,  512,  128, c3, c2, i3},        // layer 6
    {256,256,  128,  128, c3, c3, nullptr},   // layer 7
  };
  float invc[6];
  for (int s=0;s<6;s++)
    invc[s] = 1.0f / ((float)(st[s].O/4) * (float)st[s].Nq * 16.0f);

  WtParams wp;
  for (int s=0;s<6;s++){
    wp.W[s]=Wm[s];
    wp.wl[s]=ws+OFF_WL+OCoff[s];
    wp.wq[s]=ws+OFF_WQ+OCoff[s];
    wp.O[s]=st[s].O; wp.C[s]=st[s].C; wp.OC[s]=OCs[s];
  }
  k_wt_all<<<dim3(256,6), 256, 0, stream>>>(wp, stats);

  // D1: FPS stage 1 + layer-1 KNN + layer-1 GEMM
  k_fps1<<<8 + 8*1024 + 512, 256, 0, stream>>>(x, i1, c1, knn,
                                               w_in, b_in,
                                               ws+OFF_WL, ws+OFF_WQ,
                                               yk, yq);
  // D2: FPS stages 2+3 + layer-1 GATHER + layer-2 KNN (shadowed)
  k_fps23<<<8 + 512 + 8*512, 256, 0, stream>>>(x, c1, i2, i3, c2, c3, out,
                                               yk, yq, knn, vm, stats, knn2);

  for (int s=1;s<6;s++){
    const St& S = st[s];
    int rowsPB = 2048 / S.O;                       // (256/O)*GEMM_M
    int ggemm = S.Nk / rowsPB;
    int gknn  = (s == 1) ? 0 : (S.Nq + 3)/4;       // layer-2 knn done in D2
    dim3 gg(gknn + ggemm, B);
    size_t shb = (size_t)rowsPB * (S.C+1) * sizeof(float);
    const float* wl = ws+OFF_WL+OCoff[s];
    const float* wqp = ws+OFF_WQ+OCoff[s];
    const float* stp = stats + (s-1)*64;
    const float* gp  = Gm[s-1];
    const float* bp  = Bm[s-1];
    float ivc = invc[s-1];
    int npl = S.Nk >> 6;           // 64, 32, 8, 2
    if      (npl == 64)
      k_knn_gemm<64><<<gg, 256, shb, stream>>>(S.cq,S.Nq,S.ck,S.Nk,knn,
        vm, stp, gp, bp, ivc, S.C, S.O, wl, wqp, yk, yq, gknn);
    else if (npl == 32)
      k_knn_gemm<32><<<gg, 256, shb, stream>>>(S.cq,S.Nq,S.ck,S.Nk,knn,
        vm, stp, gp, bp, ivc, S.C, S.O, wl, wqp, yk, yq, gknn);
    else if (npl ==  8)
      k_knn_gemm< 8><<<gg, 256, shb, stream>>>(S.cq,S.Nq,S.ck,S.Nk,knn,
        vm, stp, gp, bp, ivc, S.C, S.O, wl, wqp, yk, yq, gknn);
    else
      k_knn_gemm< 2><<<gg, 256, shb, stream>>>(S.cq,S.Nq,S.ck,S.Nk,knn,
        vm, stp, gp, bp, ivc, S.C, S.O, wl, wqp, yk, yq, gknn);
    dim3 gs(64, B);
    const int* kidx = (s == 1) ? knn2 : knn;
    k_gather<<<gs, 256, 0, stream>>>(yk, yq, kidx, S.qmap, S.Nq, S.Nk, S.O,
                                     vm, stats + s*64);
  }
  // final layer's GN+leaky -> d_out features
  {
    dim3 gn((128*256 + 255)/256, B);
    k_norm<<<gn, 256, 0, stream>>>(vm, stats + 5*64, Gm[5], Bm[5],
                                   128, 256, invc[5], out + 8*128*3);
  }
}